// Round 7
// baseline (181.442 us; speedup 1.0000x reference)
//
#include <hip/hip_runtime.h>
#include <hip/hip_bf16.h>
#include <math.h>

static constexpr int kC = 32, kR = 255, kE = 256;

// Static device scratch (graph-capture-safe). No atomics.
__device__ float g_q0kv[768];            // [512..767] = W_v·cls + b_v
__device__ float g_qw[4 * 256];          // (q0_h^T W_k,h)*scale  [h][e]
__device__ float g_s0[4];                // score of key position 0 per head
__device__ float g_qb[4];                // (q0_h · b_k,h)*scale
__device__ float g_m[256 * 4 * 4];       // chunk max   [bc][chunk][h]
__device__ float g_l[256 * 4 * 4];       // chunk sum   [bc][chunk][h]
__device__ float g_part[256 * 4 * 4 * 256]; // partial xbar [bc][chunk][h][e]
__device__ float g_ln[256 * 256];        // LN output per token (tail -> FFN)
__device__ float g_hact[256 * 1024];     // FFN hidden activations

// bf16 weight caches, e8-major transposed: index ((e>>3)*OUT + o)*8 + (e&7).
// Consumers load uint4 at (e8*OUT+t)*16B -> lane-consecutive.
__device__ unsigned short g_wv_bf[256 * 256];    // OUT=256, IN=256
__device__ unsigned short g_wout_bf[256 * 256];  // OUT=256, IN=256
__device__ unsigned short g_w1_bf[1024 * 256];   // OUT=1024, IN=256
__device__ unsigned short g_w2_bf[256 * 1024];   // OUT=256, IN=1024

__device__ inline unsigned short f2bf(float f) {
  __hip_bfloat16 h = __float2bfloat16(f);
  return __builtin_bit_cast(unsigned short, h);
}
__device__ inline float bflo(unsigned int u) { return __uint_as_float(u << 16); }
__device__ inline float bfhi(unsigned int u) { return __uint_as_float(u & 0xffff0000u); }

// ---- Head setup: 4 blocks, one per head. q0/kc rows recomputed in-block. ----
__global__ __launch_bounds__(256) void k_heads(const float* __restrict__ cls,
                                               const float* __restrict__ w_qkv,
                                               const float* __restrict__ b_qkv) {
  const int t = threadIdx.x, wvi = t >> 6, l = t & 63;
  const int h = blockIdx.x;
  __shared__ float q0h[64];
  __shared__ float kch[64];
  {
    const int r = t >> 1, half = t & 1;
    const int row = (r < 64) ? (h * 64 + r) : (256 + h * 64 + (r - 64));
    const float4* wp = (const float4*)(w_qkv + (size_t)row * 256 + half * 128);
    const float4* cp = (const float4*)cls + half * 32;
    float a = 0.f;
#pragma unroll 8
    for (int j = 0; j < 32; ++j) {
      float4 w4 = wp[j];
      float4 cv = cp[j];
      a += w4.x * cv.x + w4.y * cv.y + w4.z * cv.z + w4.w * cv.w;
    }
    a += __shfl_xor(a, 1);
    if (half == 0) {
      const float val = a + b_qkv[row];
      if (r < 64) q0h[r] = val; else kch[r - 64] = val;
    }
  }
  __syncthreads();

  float acc = 0.f;
#pragma unroll 8
  for (int j = 0; j < 64; ++j)
    acc += q0h[j] * w_qkv[(size_t)(256 + h * 64 + j) * 256 + t];
  g_qw[h * 256 + t] = acc * 0.125f;
  if (wvi == 0) {
    const float q = q0h[l];
    float pk = q * kch[l];                    // kc includes b_k
    float pb = q * b_qkv[256 + h * 64 + l];
#pragma unroll
    for (int m = 1; m < 64; m <<= 1) {
      pk += __shfl_xor(pk, m);
      pb += __shfl_xor(pb, m);
    }
    if (l == 0) {
      g_s0[h] = pk * 0.125f;
      g_qb[h] = pb * 0.125f;
    }
  }
}

// ---- Attention chunks + rider blocks (round-2 proven config: 64-row chunks).
//   blocks 0..1023    : scores + chunk softmax + partial weighted sums
//   blocks 1024..1063 : LDS-tiled transposing bf16 casts
//   blocks 1064..1127 : v rows of W_qkv·cls + b (wave-per-row 1KB dot) ----
__global__ __launch_bounds__(256) void k_attn(const float* __restrict__ x,
                                              const int* __restrict__ real_cols,
                                              const int* __restrict__ real_rows,
                                              const float* __restrict__ cls,
                                              const float* __restrict__ w_qkv,
                                              const float* __restrict__ b_qkv,
                                              const float* __restrict__ w_out,
                                              const float* __restrict__ w1,
                                              const float* __restrict__ w2) {
  const int t = threadIdx.x, wv = t >> 6, l = t & 63;
  const int bid = blockIdx.x;
  __shared__ __align__(16) char smem[71680];

  if (bid >= 1064) {  // ---- v rows 512..767: wave-per-row dot ----
    const int row = 512 + (bid - 1064) * 4 + wv;
    float4 w4 = *((const float4*)(w_qkv + (size_t)row * 256) + l);
    float4 c4 = *((const float4*)cls + l);
    float a = w4.x * c4.x + w4.y * c4.y + w4.z * c4.z + w4.w * c4.w;
#pragma unroll
    for (int m = 1; m < 64; m <<= 1) a += __shfl_xor(a, m);
    if (l == 0) g_q0kv[row] = a + b_qkv[row];
    return;
  }

  if (bid >= 1024) {  // ---- cast tiles: 64 out-rows x 256 in-cols ----
    const int u = bid - 1024;  // 0..39
    const float* src;
    unsigned short* dst;
    int R, C, o0, e0;
    if (u < 4) { src = w_qkv + 512 * 256; dst = g_wv_bf; R = 256; C = 256; o0 = u * 64; e0 = 0; }
    else if (u < 8) { src = w_out; dst = g_wout_bf; R = 256; C = 256; o0 = (u - 4) * 64; e0 = 0; }
    else if (u < 24) { src = w1; dst = g_w1_bf; R = 1024; C = 256; o0 = (u - 8) * 64; e0 = 0; }
    else { const int v = u - 24; src = w2; dst = g_w2_bf; R = 256; C = 1024; o0 = (v >> 2) * 64; e0 = (v & 3) * 256; }

    unsigned short* tile = (unsigned short*)smem;  // 64*260 ushort = 33280 B
    for (int r = wv; r < 64; r += 4) {
      float4 v = *((const float4*)(src + (size_t)(o0 + r) * C + e0) + l);
      ushort4 ov;
      ov.x = f2bf(v.x); ov.y = f2bf(v.y); ov.z = f2bf(v.z); ov.w = f2bf(v.w);
      *(ushort4*)&tile[r * 260 + 4 * l] = ov;
    }
    __syncthreads();
    const int e80 = e0 >> 3;
    for (int e8l = wv; e8l < 32; e8l += 4) {
      const unsigned int* tp = (const unsigned int*)&tile[l * 260 + e8l * 8];
      uint4 o;
      o.x = tp[0]; o.y = tp[1]; o.z = tp[2]; o.w = tp[3];
      *(uint4*)(dst + ((size_t)(e80 + e8l) * R + o0 + l) * 8) = o;
    }
    return;
  }

  // ---- attention chunk blocks (proven 64-row version) ----
  const int bc = bid >> 2, chunk = bid & 3;
  const int b = bc >> 5, c = bc & 31;
  if (c >= real_cols[b]) return;
  const int rr = real_rows[b];
  const int r0 = chunk * 64;
  const int nr = min(64, rr - r0);
  if (nr <= 0) return;

  float (*xs)[260] = (float(*)[260])smem;                    // 66560 B
  float (*qws)[256] = (float(*)[256])(smem + 66560);         //  4096 B
  float (*ps)[64] = (float(*)[64])(smem + 70656);            //  1024 B

#pragma unroll
  for (int i = 0; i < 4; ++i) qws[i][t] = g_qw[i * 256 + t];

  const float* xb = x + ((size_t)bc * kR + r0) * kE;
  for (int r = wv; r < nr; r += 4)
    *(float4*)&xs[r][4 * l] = *(const float4*)(xb + (size_t)r * kE + 4 * l);
  __syncthreads();

  const int h = wv, row = l;
  float acc = 0.f;
  const float4* qrow = (const float4*)&qws[h][0];
  const float4* xrow = (const float4*)&xs[row][0];
#pragma unroll 8
  for (int e4 = 0; e4 < 64; ++e4) {
    float4 q4 = qrow[e4];
    float4 x4 = xrow[e4];
    acc += q4.x * x4.x + q4.y * x4.y + q4.z * x4.z + q4.w * x4.w;
  }
  float s = (row < nr) ? acc + g_qb[h] : -1e30f;
  float mx = s;
#pragma unroll
  for (int m = 1; m < 64; m <<= 1) mx = fmaxf(mx, __shfl_xor(mx, m));
  float p = (row < nr) ? __expf(s - mx) : 0.f;
  float lsum = p;
#pragma unroll
  for (int m = 1; m < 64; m <<= 1) lsum += __shfl_xor(lsum, m);
  ps[h][row] = p;
  if (l == 0) {
    g_m[(bc * 4 + chunk) * 4 + h] = mx;
    g_l[(bc * 4 + chunk) * 4 + h] = lsum;
  }
  __syncthreads();

  float a0 = 0.f, a1 = 0.f, a2 = 0.f, a3 = 0.f;
  for (int r2 = 0; r2 < nr; ++r2) {
    float xv = xs[r2][t];
    a0 += ps[0][r2] * xv;
    a1 += ps[1][r2] * xv;
    a2 += ps[2][r2] * xv;
    a3 += ps[3][r2] * xv;
  }
  float* pp = g_part + (size_t)(bc * 4 + chunk) * 4 * 256;
  pp[0 * 256 + t] = a0;
  pp[1 * 256 + t] = a1;
  pp[2 * 256 + t] = a2;
  pp[3 * 256 + t] = a3;
}

// ---- Per-token tail, WIDE (round-2 structure, LDS acts — round-6 lesson:
//      LDS broadcast beats uniform-VMEM 2x): merge -> ctx -> mha -> LN -> g_ln.
//      FFN extracted to balanced kernels (4x weight reuse + full-chip balance). ----
__global__ __launch_bounds__(1024) void k_tail(const int* __restrict__ real_cols,
                                               const int* __restrict__ real_rows,
                                               const float* __restrict__ b_qkv,
                                               const float* __restrict__ b_out,
                                               const float* __restrict__ ln_g,
                                               const float* __restrict__ ln_b) {
  const int bc = blockIdx.x, b = bc >> 5, c = bc & 31;
  const int t = threadIdx.x, wv = t >> 6, l = t & 63;
  if (c >= real_cols[b]) return;  // g_ln stays stale-but-finite; masked later
  const int rr = real_rows[b];
  const int nch = (rr + 63) >> 6;

  __shared__ float xb[4][256];
  __shared__ float part[4][256];  // split-K partials (reused per phase)
  __shared__ float ctxs[256];
  __shared__ float al[4][4];
  __shared__ float p0s[4];
  __shared__ float rb[2][4];

  if (t < 4) {  // flash-merge chunk stats, head h = t
    const int h = t;
    const float s0 = g_s0[h];
    float M = s0;
    for (int ch = 0; ch < nch; ++ch) M = fmaxf(M, g_m[(bc * 4 + ch) * 4 + h]);
    float lt = __expf(s0 - M);
    const float w0 = lt;
    float av[4] = {0.f, 0.f, 0.f, 0.f};
    for (int ch = 0; ch < nch; ++ch) {
      float e = __expf(g_m[(bc * 4 + ch) * 4 + h] - M);
      av[ch] = e;
      lt += g_l[(bc * 4 + ch) * 4 + h] * e;
    }
    const float inv = 1.f / lt;
#pragma unroll
    for (int ch = 0; ch < 4; ++ch) al[h][ch] = av[ch] * inv;
    p0s[h] = w0 * inv;
  }
  __syncthreads();

  {  // xbar merge: thread t -> (h = t>>8, e = t&255)
    const int h = t >> 8, e = t & 255;
    float a = 0.f;
    for (int ch = 0; ch < nch; ++ch)
      a += al[h][ch] * g_part[(size_t)(bc * 4 + ch) * 1024 + h * 256 + e];
    xb[h][e] = a;
  }
  __syncthreads();

  {  // ctx: f = t&255, split-K group q = t>>8 handles e8 in [8q, 8q+8)
    const int f = t & 255, q = t >> 8, h = f >> 6;
    const uint4* wr = (const uint4*)g_wv_bf;
    const float4* v4p = (const float4*)&xb[h][0];
    float acc = 0.f;
#pragma unroll
    for (int i = 0; i < 8; ++i) {
      const int e8 = q * 8 + i;
      uint4 w = wr[e8 * 256 + f];
      float4 a = v4p[2 * e8], bb = v4p[2 * e8 + 1];
      acc += bflo(w.x) * a.x + bfhi(w.x) * a.y + bflo(w.y) * a.z + bfhi(w.y) * a.w +
             bflo(w.z) * bb.x + bfhi(w.z) * bb.y + bflo(w.w) * bb.z + bfhi(w.w) * bb.w;
    }
    part[q][f] = acc;
  }
  __syncthreads();
  if (t < 256) {
    const int h = t >> 6;
    const float p0 = p0s[h];
    ctxs[t] = part[0][t] + part[1][t] + part[2][t] + part[3][t] +
              p0 * g_q0kv[512 + t] + (1.f - p0) * b_qkv[512 + t];
  }
  __syncthreads();

  {  // mha: g = t&255, split-K-4 over e8; e8-major W_out
    const int g = t & 255, q = t >> 8;
    const uint4* wr = (const uint4*)g_wout_bf;
    const float4* c4 = (const float4*)&ctxs[0];
    float acc = 0.f;
#pragma unroll
    for (int i = 0; i < 8; ++i) {
      const int e8 = q * 8 + i;
      uint4 w = wr[e8 * 256 + g];
      float4 a = c4[2 * e8], bb = c4[2 * e8 + 1];
      acc += bflo(w.x) * a.x + bfhi(w.x) * a.y + bflo(w.y) * a.z + bfhi(w.y) * a.w +
             bflo(w.z) * bb.x + bfhi(w.z) * bb.y + bflo(w.w) * bb.z + bfhi(w.w) * bb.w;
    }
    part[q][g] = acc;
  }
  __syncthreads();
  if (t < 256) {
    const float mh = part[0][t] + part[1][t] + part[2][t] + part[3][t] + b_out[t];
    float s1 = mh, s2 = mh * mh;
#pragma unroll
    for (int m = 1; m < 64; m <<= 1) {
      s1 += __shfl_xor(s1, m);
      s2 += __shfl_xor(s2, m);
    }
    if (l == 0) {
      rb[0][wv] = s1;
      rb[1][wv] = s2;
    }
    __syncthreads();
    const float mu = (rb[0][0] + rb[0][1] + rb[0][2] + rb[0][3]) * (1.f / 256.f);
    const float msq = (rb[1][0] + rb[1][1] + rb[1][2] + rb[1][3]) * (1.f / 256.f);
    const float var = msq - mu * mu;
    g_ln[(size_t)bc * 256 + t] =
        (mh - mu) * rsqrtf(var + 1e-5f) * ln_g[t] + ln_b[t];
  } else {
    __syncthreads();
  }
}

// ---- FFN1: relu(W1·ln+b1); 4 tokens x 128-f slice; 512 blocks (balanced). ----
__global__ __launch_bounds__(256) void k_ffn1(const float* __restrict__ b1,
                                              const int* __restrict__ real_cols) {
  const int tok0 = blockIdx.x * 4;
  const int b = tok0 >> 5, c0 = tok0 & 31;
  if (c0 >= real_cols[b]) return;
  __shared__ float lns[4][256];
  const int t = threadIdx.x;
  const int f0 = blockIdx.y * 128;
#pragma unroll
  for (int i = 0; i < 4; ++i) lns[i][t] = g_ln[(size_t)(tok0 + i) * 256 + t];
  __syncthreads();
  const int f = f0 + (t & 127), tp = t >> 7;  // tp uniform per wave-pair
  const uint4* wr = (const uint4*)g_w1_bf;
  const float bb = b1[f];
  float acc0 = bb, acc1 = bb;
  const float4* l0 = (const float4*)&lns[tp * 2][0];
  const float4* l1 = (const float4*)&lns[tp * 2 + 1][0];
#pragma unroll 8
  for (int e8 = 0; e8 < 32; ++e8) {
    uint4 w = wr[e8 * 1024 + f];
    const float w0 = bflo(w.x), w1v = bfhi(w.x), w2v = bflo(w.y), w3 = bfhi(w.y);
    const float w4v = bflo(w.z), w5 = bfhi(w.z), w6 = bflo(w.w), w7 = bfhi(w.w);
    float4 a = l0[2 * e8], bbv = l0[2 * e8 + 1];
    acc0 += w0 * a.x + w1v * a.y + w2v * a.z + w3 * a.w +
            w4v * bbv.x + w5 * bbv.y + w6 * bbv.z + w7 * bbv.w;
    a = l1[2 * e8]; bbv = l1[2 * e8 + 1];
    acc1 += w0 * a.x + w1v * a.y + w2v * a.z + w3 * a.w +
            w4v * bbv.x + w5 * bbv.y + w6 * bbv.z + w7 * bbv.w;
  }
  g_hact[(size_t)(tok0 + tp * 2) * 1024 + f] = fmaxf(acc0, 0.f);
  g_hact[(size_t)(tok0 + tp * 2 + 1) * 1024 + f] = fmaxf(acc1, 0.f);
}

// ---- FFN2 + residual + mask; 4 tokens x 32-e slice, split-K-2; 512 blocks ----
__global__ __launch_bounds__(256) void k_ffn2(const float* __restrict__ b2,
                                              const int* __restrict__ real_cols,
                                              float* __restrict__ out) {
  const int t = threadIdx.x;
  const int tok0 = blockIdx.x * 4, e0 = blockIdx.y * 32;
  const int b = tok0 >> 5, c0 = tok0 & 31;
  const int ncols = real_cols[b];
  if (c0 >= ncols) {  // whole group invalid: write the zero mask slice
    if (t < 128) out[(size_t)(tok0 + (t >> 5)) * 256 + e0 + (t & 31)] = 0.f;
    return;
  }
  __shared__ float hs[4][1024];  // 16 KB
  __shared__ float part[2][4][32];
  {
    const float4* hsrc = (const float4*)(g_hact + (size_t)tok0 * 1024);
    float4* hd = (float4*)&hs[0][0];
#pragma unroll
    for (int j = 0; j < 4; ++j) hd[t + 256 * j] = hsrc[t + 256 * j];
  }
  __syncthreads();
  const int e = e0 + (t & 31), i = (t >> 5) & 3, q = t >> 7;
  const uint4* wr = (const uint4*)g_w2_bf;
  const float4* h4 = (const float4*)&hs[i][0];
  float acc = 0.f;
#pragma unroll 8
  for (int f8i = 0; f8i < 64; ++f8i) {
    const int f8 = q * 64 + f8i;
    uint4 w = wr[f8 * 256 + e];
    float4 a = h4[2 * f8], bb = h4[2 * f8 + 1];
    acc += bflo(w.x) * a.x + bfhi(w.x) * a.y + bflo(w.y) * a.z + bfhi(w.y) * a.w +
           bflo(w.z) * bb.x + bfhi(w.z) * bb.y + bflo(w.w) * bb.z + bfhi(w.w) * bb.w;
  }
  part[q][i][t & 31] = acc;
  __syncthreads();
  if (t < 128) {
    const int ii = t >> 5, ee = e0 + (t & 31);
    const int tok = tok0 + ii, c = tok & 31;
    const float r = part[0][ii][t & 31] + part[1][ii][t & 31] + b2[ee];
    const float lnv = g_ln[(size_t)tok * 256 + ee];
    out[(size_t)tok * 256 + ee] = (c < ncols) ? (lnv + r) : 0.f;
  }
}

extern "C" void kernel_launch(void* const* d_in, const int* in_sizes, int n_in,
                              void* d_out, int out_size, void* d_ws, size_t ws_size,
                              hipStream_t stream) {
  const float* x = (const float*)d_in[0];
  const int* real_cols = (const int*)d_in[1];
  const int* real_rows = (const int*)d_in[2];
  const float* cls = (const float*)d_in[3];
  const float* w_qkv = (const float*)d_in[4];
  const float* b_qkv = (const float*)d_in[5];
  const float* w_out = (const float*)d_in[6];
  const float* b_out = (const float*)d_in[7];
  const float* ln_g = (const float*)d_in[8];
  const float* ln_b = (const float*)d_in[9];
  const float* w1 = (const float*)d_in[10];
  const float* b1 = (const float*)d_in[11];
  const float* w2 = (const float*)d_in[12];
  const float* b2 = (const float*)d_in[13];
  float* out = (float*)d_out;
  (void)in_sizes; (void)n_in; (void)out_size; (void)d_ws; (void)ws_size;

  k_heads<<<4, 256, 0, stream>>>(cls, w_qkv, b_qkv);
  k_attn<<<1128, 256, 0, stream>>>(x, real_cols, real_rows, cls, w_qkv, b_qkv, w_out, w1, w2);
  k_tail<<<256, 1024, 0, stream>>>(real_cols, real_rows, b_qkv, b_out, ln_g, ln_b);
  k_ffn1<<<dim3(64, 8), 256, 0, stream>>>(b1, real_cols);
  k_ffn2<<<dim3(64, 8), 256, 0, stream>>>(b2, real_cols, out);
}

// Round 8
// 155.183 us; speedup vs baseline: 1.1692x; 1.1692x over previous
//
#include <hip/hip_runtime.h>
#include <hip/hip_bf16.h>
#include <math.h>

static constexpr int kC = 32, kR = 255, kE = 256;

typedef _Float16 half2v __attribute__((ext_vector_type(2)));

// Static device scratch (graph-capture-safe). No atomics.
__device__ float g_q0kv[768];            // [512..767] = W_v·cls + b_v
__device__ float g_qw[4 * 256];          // (q0_h^T W_k,h)*scale  [h][e]
__device__ float g_s0[4];                // score of key position 0 per head
__device__ float g_qb[4];                // (q0_h · b_k,h)*scale
__device__ float g_m[256 * 4 * 4];       // chunk max   [bc][chunk][h]
__device__ float g_l[256 * 4 * 4];       // chunk sum   [bc][chunk][h]
__device__ float g_part[256 * 4 * 4 * 256]; // partial xbar [bc][chunk][h][e]

// f16 weight caches, e8-major transposed: index ((e>>3)*OUT + o)*8 + (e&7).
// Consumers load uint4 at (e8*OUT+t)*16B = 8 f16 -> 4 half2 dot2 operands.
// (fp16 has 10 mantissa bits vs bf16's 7: weight rounding error DROPS.)
__device__ unsigned short g_wv_hf[256 * 256];    // OUT=256, IN=256
__device__ unsigned short g_wout_hf[256 * 256];  // OUT=256, IN=256
__device__ unsigned short g_w1_hf[1024 * 256];   // OUT=1024, IN=256
__device__ unsigned short g_w2_hf[256 * 1024];   // OUT=256, IN=1024

__device__ inline unsigned short f2h(float f) {
  _Float16 h = (_Float16)f;
  return __builtin_bit_cast(unsigned short, h);
}
__device__ inline half2v uph(unsigned int u) { return __builtin_bit_cast(half2v, u); }

#if __has_builtin(__builtin_amdgcn_fdot2)
__device__ inline float dot2(unsigned int w, unsigned int a, float acc) {
  return __builtin_amdgcn_fdot2(uph(w), uph(a), acc, false);
}
#else
__device__ inline float dot2(unsigned int w, unsigned int a, float acc) {
  half2v wv = uph(w), av = uph(a);
  return acc + (float)wv[0] * (float)av[0] + (float)wv[1] * (float)av[1];
}
#endif

// ---- Head setup: 4 blocks, one per head. q0/kc rows recomputed in-block. ----
__global__ __launch_bounds__(256) void k_heads(const float* __restrict__ cls,
                                               const float* __restrict__ w_qkv,
                                               const float* __restrict__ b_qkv) {
  const int t = threadIdx.x, wvi = t >> 6, l = t & 63;
  const int h = blockIdx.x;
  __shared__ float q0h[64];
  __shared__ float kch[64];
  {
    const int r = t >> 1, half = t & 1;
    const int row = (r < 64) ? (h * 64 + r) : (256 + h * 64 + (r - 64));
    const float4* wp = (const float4*)(w_qkv + (size_t)row * 256 + half * 128);
    const float4* cp = (const float4*)cls + half * 32;
    float a = 0.f;
#pragma unroll 8
    for (int j = 0; j < 32; ++j) {
      float4 w4 = wp[j];
      float4 cv = cp[j];
      a += w4.x * cv.x + w4.y * cv.y + w4.z * cv.z + w4.w * cv.w;
    }
    a += __shfl_xor(a, 1);
    if (half == 0) {
      const float val = a + b_qkv[row];
      if (r < 64) q0h[r] = val; else kch[r - 64] = val;
    }
  }
  __syncthreads();

  float acc = 0.f;
#pragma unroll 8
  for (int j = 0; j < 64; ++j)
    acc += q0h[j] * w_qkv[(size_t)(256 + h * 64 + j) * 256 + t];
  g_qw[h * 256 + t] = acc * 0.125f;
  if (wvi == 0) {
    const float q = q0h[l];
    float pk = q * kch[l];                    // kc includes b_k
    float pb = q * b_qkv[256 + h * 64 + l];
#pragma unroll
    for (int m = 1; m < 64; m <<= 1) {
      pk += __shfl_xor(pk, m);
      pb += __shfl_xor(pb, m);
    }
    if (l == 0) {
      g_s0[h] = pk * 0.125f;
      g_qb[h] = pb * 0.125f;
    }
  }
}

// ---- Attention chunks + rider blocks (round-2 proven config: 64-row chunks).
//   blocks 0..1023    : scores + chunk softmax + partial weighted sums
//   blocks 1024..1063 : LDS-tiled transposing f16 casts (feed k_token only)
//   blocks 1064..1127 : v rows of W_qkv·cls + b (wave-per-row 1KB dot) ----
__global__ __launch_bounds__(256) void k_attn(const float* __restrict__ x,
                                              const int* __restrict__ real_cols,
                                              const int* __restrict__ real_rows,
                                              const float* __restrict__ cls,
                                              const float* __restrict__ w_qkv,
                                              const float* __restrict__ b_qkv,
                                              const float* __restrict__ w_out,
                                              const float* __restrict__ w1,
                                              const float* __restrict__ w2) {
  const int t = threadIdx.x, wv = t >> 6, l = t & 63;
  const int bid = blockIdx.x;
  __shared__ __align__(16) char smem[71680];

  if (bid >= 1064) {  // ---- v rows 512..767: wave-per-row dot ----
    const int row = 512 + (bid - 1064) * 4 + wv;
    float4 w4 = *((const float4*)(w_qkv + (size_t)row * 256) + l);
    float4 c4 = *((const float4*)cls + l);
    float a = w4.x * c4.x + w4.y * c4.y + w4.z * c4.z + w4.w * c4.w;
#pragma unroll
    for (int m = 1; m < 64; m <<= 1) a += __shfl_xor(a, m);
    if (l == 0) g_q0kv[row] = a + b_qkv[row];
    return;
  }

  if (bid >= 1024) {  // ---- cast tiles: 64 out-rows x 256 in-cols ----
    const int u = bid - 1024;  // 0..39
    const float* src;
    unsigned short* dst;
    int R, C, o0, e0;
    if (u < 4) { src = w_qkv + 512 * 256; dst = g_wv_hf; R = 256; C = 256; o0 = u * 64; e0 = 0; }
    else if (u < 8) { src = w_out; dst = g_wout_hf; R = 256; C = 256; o0 = (u - 4) * 64; e0 = 0; }
    else if (u < 24) { src = w1; dst = g_w1_hf; R = 1024; C = 256; o0 = (u - 8) * 64; e0 = 0; }
    else { const int v = u - 24; src = w2; dst = g_w2_hf; R = 256; C = 1024; o0 = (v >> 2) * 64; e0 = (v & 3) * 256; }

    unsigned short* tile = (unsigned short*)smem;  // 64*260 ushort = 33280 B
    for (int r = wv; r < 64; r += 4) {
      float4 v = *((const float4*)(src + (size_t)(o0 + r) * C + e0) + l);
      ushort4 ov;
      ov.x = f2h(v.x); ov.y = f2h(v.y); ov.z = f2h(v.z); ov.w = f2h(v.w);
      *(ushort4*)&tile[r * 260 + 4 * l] = ov;
    }
    __syncthreads();
    const int e80 = e0 >> 3;
    for (int e8l = wv; e8l < 32; e8l += 4) {
      const unsigned int* tp = (const unsigned int*)&tile[l * 260 + e8l * 8];
      uint4 o;
      o.x = tp[0]; o.y = tp[1]; o.z = tp[2]; o.w = tp[3];
      *(uint4*)(dst + ((size_t)(e80 + e8l) * R + o0 + l) * 8) = o;
    }
    return;
  }

  // ---- attention chunk blocks (proven 64-row version) ----
  const int bc = bid >> 2, chunk = bid & 3;
  const int b = bc >> 5, c = bc & 31;
  if (c >= real_cols[b]) return;
  const int rr = real_rows[b];
  const int r0 = chunk * 64;
  const int nr = min(64, rr - r0);
  if (nr <= 0) return;

  float (*xs)[260] = (float(*)[260])smem;                    // 66560 B
  float (*qws)[256] = (float(*)[256])(smem + 66560);         //  4096 B
  float (*ps)[64] = (float(*)[64])(smem + 70656);            //  1024 B

#pragma unroll
  for (int i = 0; i < 4; ++i) qws[i][t] = g_qw[i * 256 + t];

  const float* xb = x + ((size_t)bc * kR + r0) * kE;
  for (int r = wv; r < nr; r += 4)
    *(float4*)&xs[r][4 * l] = *(const float4*)(xb + (size_t)r * kE + 4 * l);
  __syncthreads();

  const int h = wv, row = l;
  float acc = 0.f;
  const float4* qrow = (const float4*)&qws[h][0];
  const float4* xrow = (const float4*)&xs[row][0];
#pragma unroll 8
  for (int e4 = 0; e4 < 64; ++e4) {
    float4 q4 = qrow[e4];
    float4 x4 = xrow[e4];
    acc += q4.x * x4.x + q4.y * x4.y + q4.z * x4.z + q4.w * x4.w;
  }
  float s = (row < nr) ? acc + g_qb[h] : -1e30f;
  float mx = s;
#pragma unroll
  for (int m = 1; m < 64; m <<= 1) mx = fmaxf(mx, __shfl_xor(mx, m));
  float p = (row < nr) ? __expf(s - mx) : 0.f;
  float lsum = p;
#pragma unroll
  for (int m = 1; m < 64; m <<= 1) lsum += __shfl_xor(lsum, m);
  ps[h][row] = p;
  if (l == 0) {
    g_m[(bc * 4 + chunk) * 4 + h] = mx;
    g_l[(bc * 4 + chunk) * 4 + h] = lsum;
  }
  __syncthreads();

  float a0 = 0.f, a1 = 0.f, a2 = 0.f, a3 = 0.f;
  for (int r2 = 0; r2 < nr; ++r2) {
    float xv = xs[r2][t];
    a0 += ps[0][r2] * xv;
    a1 += ps[1][r2] * xv;
    a2 += ps[2][r2] * xv;
    a3 += ps[3][r2] * xv;
  }
  float* pp = g_part + (size_t)(bc * 4 + chunk) * 4 * 256;
  pp[0 * 256 + t] = a0;
  pp[1 * 256 + t] = a1;
  pp[2 * 256 + t] = a2;
  pp[3 * 256 + t] = a3;
}

// ---- Fused per-token tail, WIDE (round-2 proven structure: 1024 thr, LDS
//      acts, split-K-4) with ONE change: inner products via v_dot2_f32_f16
//      (f16 weights + f16 act mirrors in LDS). Per 8 MACs: 1 VMEM + 1 ds_read
//      + 4 dot2 vs 1 VMEM + 2 ds_read + 8 unpack + 8 FMA. Residual/LN fp32. ----
__global__ __launch_bounds__(1024) void k_token(const int* __restrict__ real_cols,
                                                const int* __restrict__ real_rows,
                                                const float* __restrict__ b_qkv,
                                                const float* __restrict__ b_out,
                                                const float* __restrict__ ln_g,
                                                const float* __restrict__ ln_b,
                                                const float* __restrict__ b1,
                                                const float* __restrict__ b2,
                                                float* __restrict__ out) {
  const int bc = blockIdx.x, b = bc >> 5, c = bc & 31;
  const int t = threadIdx.x, wv = t >> 6, l = t & 63;
  if (c >= real_cols[b]) {  // masked column: write the zero mask and leave
    if (t < 256) out[(size_t)bc * 256 + t] = 0.f;
    return;
  }
  const int rr = real_rows[b];
  const int nch = (rr + 63) >> 6;

  __shared__ float part[4][256];            // split-K partials (reused per phase)
  __shared__ unsigned short xh[4 * 256];    // xbar, f16
  __shared__ unsigned short ctxh[256];      // ctx, f16
  __shared__ float lnsf[256];               // LN output fp32 (exact residual)
  __shared__ unsigned short lnsh[256];      // LN output f16 (dot operand)
  __shared__ unsigned short hsh[1024];      // FFN hidden, f16
  __shared__ float al[4][4];
  __shared__ float p0s[4];
  __shared__ float rb[2][4];

  if (t < 4) {  // flash-merge chunk stats, head h = t
    const int h = t;
    const float s0 = g_s0[h];
    float M = s0;
    for (int ch = 0; ch < nch; ++ch) M = fmaxf(M, g_m[(bc * 4 + ch) * 4 + h]);
    float lt = __expf(s0 - M);
    const float w0 = lt;
    float av[4] = {0.f, 0.f, 0.f, 0.f};
    for (int ch = 0; ch < nch; ++ch) {
      float e = __expf(g_m[(bc * 4 + ch) * 4 + h] - M);
      av[ch] = e;
      lt += g_l[(bc * 4 + ch) * 4 + h] * e;
    }
    const float inv = 1.f / lt;
#pragma unroll
    for (int ch = 0; ch < 4; ++ch) al[h][ch] = av[ch] * inv;
    p0s[h] = w0 * inv;
  }
  __syncthreads();

  {  // xbar merge: thread t -> (h = t>>8, e = t&255); f16 mirror only
    const int h = t >> 8, e = t & 255;
    float a = 0.f;
    for (int ch = 0; ch < nch; ++ch)
      a += al[h][ch] * g_part[(size_t)(bc * 4 + ch) * 1024 + h * 256 + e];
    xh[h * 256 + e] = f2h(a);
  }
  __syncthreads();

  {  // ctx: f = t&255, split-K group q = t>>8 handles e8 in [8q, 8q+8)
    const int f = t & 255, q = t >> 8, h = f >> 6;
    const uint4* wr = (const uint4*)g_wv_hf;
    const uint4* ap = (const uint4*)&xh[h * 256];
    float acc = 0.f;
#pragma unroll
    for (int i = 0; i < 8; ++i) {
      const int e8 = q * 8 + i;
      uint4 w = wr[e8 * 256 + f];
      uint4 a = ap[e8];
      acc = dot2(w.x, a.x, acc);
      acc = dot2(w.y, a.y, acc);
      acc = dot2(w.z, a.z, acc);
      acc = dot2(w.w, a.w, acc);
    }
    part[q][f] = acc;
  }
  __syncthreads();
  if (t < 256) {
    const int h = t >> 6;
    const float p0 = p0s[h];
    ctxh[t] = f2h(part[0][t] + part[1][t] + part[2][t] + part[3][t] +
                  p0 * g_q0kv[512 + t] + (1.f - p0) * b_qkv[512 + t]);
  }
  __syncthreads();

  {  // mha: g = t&255, split-K-4 over e8
    const int g = t & 255, q = t >> 8;
    const uint4* wr = (const uint4*)g_wout_hf;
    const uint4* cp = (const uint4*)&ctxh[0];
    float acc = 0.f;
#pragma unroll
    for (int i = 0; i < 8; ++i) {
      const int e8 = q * 8 + i;
      uint4 w = wr[e8 * 256 + g];
      uint4 a = cp[e8];
      acc = dot2(w.x, a.x, acc);
      acc = dot2(w.y, a.y, acc);
      acc = dot2(w.z, a.z, acc);
      acc = dot2(w.w, a.w, acc);
    }
    part[q][g] = acc;
  }
  __syncthreads();
  if (t < 256) {
    const float mh = part[0][t] + part[1][t] + part[2][t] + part[3][t] + b_out[t];
    float s1 = mh, s2 = mh * mh;
#pragma unroll
    for (int m = 1; m < 64; m <<= 1) {
      s1 += __shfl_xor(s1, m);
      s2 += __shfl_xor(s2, m);
    }
    if (l == 0) {
      rb[0][wv] = s1;
      rb[1][wv] = s2;
    }
    __syncthreads();
    const float mu = (rb[0][0] + rb[0][1] + rb[0][2] + rb[0][3]) * (1.f / 256.f);
    const float msq = (rb[1][0] + rb[1][1] + rb[1][2] + rb[1][3]) * (1.f / 256.f);
    const float var = msq - mu * mu;
    const float lnv = (mh - mu) * rsqrtf(var + 1e-5f) * ln_g[t] + ln_b[t];
    lnsf[t] = lnv;
    lnsh[t] = f2h(lnv);
  } else {
    __syncthreads();
  }
  __syncthreads();

  {  // FFN1: thread t computes f = t; dual accumulators break the dep chain
    const uint4* wr = (const uint4*)g_w1_hf;
    const uint4* lp = (const uint4*)&lnsh[0];
    float acc0 = b1[t], acc1 = 0.f;
#pragma unroll 8
    for (int e8 = 0; e8 < 32; ++e8) {
      uint4 w = wr[e8 * 1024 + t];
      uint4 a = lp[e8];
      acc0 = dot2(w.x, a.x, acc0);
      acc1 = dot2(w.y, a.y, acc1);
      acc0 = dot2(w.z, a.z, acc0);
      acc1 = dot2(w.w, a.w, acc1);
    }
    hsh[t] = f2h(fmaxf(acc0 + acc1, 0.f));
  }
  __syncthreads();

  {  // FFN2: e = t&255, split-K group q = t>>8 over f8; dual accumulators
    const int e = t & 255, q = t >> 8;
    const uint4* wr = (const uint4*)g_w2_hf;
    const uint4* hp = (const uint4*)&hsh[0];
    float acc0 = 0.f, acc1 = 0.f;
#pragma unroll 8
    for (int i = 0; i < 32; ++i) {
      const int f8 = q * 32 + i;
      uint4 w = wr[f8 * 256 + e];
      uint4 a = hp[f8];
      acc0 = dot2(w.x, a.x, acc0);
      acc1 = dot2(w.y, a.y, acc1);
      acc0 = dot2(w.z, a.z, acc0);
      acc1 = dot2(w.w, a.w, acc1);
    }
    part[q][e] = acc0 + acc1;
  }
  __syncthreads();
  if (t < 256)
    out[(size_t)bc * 256 + t] =
        lnsf[t] + part[0][t] + part[1][t] + part[2][t] + part[3][t] + b2[t];
}

extern "C" void kernel_launch(void* const* d_in, const int* in_sizes, int n_in,
                              void* d_out, int out_size, void* d_ws, size_t ws_size,
                              hipStream_t stream) {
  const float* x = (const float*)d_in[0];
  const int* real_cols = (const int*)d_in[1];
  const int* real_rows = (const int*)d_in[2];
  const float* cls = (const float*)d_in[3];
  const float* w_qkv = (const float*)d_in[4];
  const float* b_qkv = (const float*)d_in[5];
  const float* w_out = (const float*)d_in[6];
  const float* b_out = (const float*)d_in[7];
  const float* ln_g = (const float*)d_in[8];
  const float* ln_b = (const float*)d_in[9];
  const float* w1 = (const float*)d_in[10];
  const float* b1 = (const float*)d_in[11];
  const float* w2 = (const float*)d_in[12];
  const float* b2 = (const float*)d_in[13];
  float* out = (float*)d_out;
  (void)in_sizes; (void)n_in; (void)out_size; (void)d_ws; (void)ws_size;

  k_heads<<<4, 256, 0, stream>>>(cls, w_qkv, b_qkv);
  k_attn<<<1128, 256, 0, stream>>>(x, real_cols, real_rows, cls, w_qkv, b_qkv, w_out, w1, w2);
  k_token<<<256, 1024, 0, stream>>>(real_cols, real_rows, b_qkv, b_out, ln_g, ln_b, b1, b2, out);
}

// Round 9
// 153.945 us; speedup vs baseline: 1.1786x; 1.0080x over previous
//
#include <hip/hip_runtime.h>
#include <hip/hip_bf16.h>
#include <math.h>

static constexpr int kC = 32, kR = 255, kE = 256;

typedef _Float16 half2v __attribute__((ext_vector_type(2)));

// Static device scratch (graph-capture-safe). No atomics.
__device__ float g_q0kv[768];            // [512..767] = W_v·cls + b_v
__device__ float g_qw[4 * 256];          // (q0_h^T W_k,h)*scale  [h][e]
__device__ float g_s0[4];                // score of key position 0 per head
__device__ float g_qb[4];                // (q0_h · b_k,h)*scale
__device__ float g_m[256 * 4 * 4];       // chunk max   [bc][chunk][h]
__device__ float g_l[256 * 4 * 4];       // chunk sum   [bc][chunk][h]
__device__ float g_part[256 * 4 * 4 * 256]; // partial xbar [bc][chunk][h][e]

// f16 weight caches, e8-major transposed: index ((e>>3)*OUT + o)*8 + (e&7).
// Consumers load uint4 at (e8*OUT+t)*16B = 8 f16 -> 4 half2 dot2 operands.
__device__ unsigned short g_wv_hf[256 * 256];    // OUT=256, IN=256
__device__ unsigned short g_wout_hf[256 * 256];  // OUT=256, IN=256
__device__ unsigned short g_w1_hf[1024 * 256];   // OUT=1024, IN=256
__device__ unsigned short g_w2_hf[256 * 1024];   // OUT=256, IN=1024

__device__ inline unsigned short f2h(float f) {
  _Float16 h = (_Float16)f;
  return __builtin_bit_cast(unsigned short, h);
}
__device__ inline half2v uph(unsigned int u) { return __builtin_bit_cast(half2v, u); }

#if __has_builtin(__builtin_amdgcn_fdot2)
__device__ inline float dot2(unsigned int w, unsigned int a, float acc) {
  return __builtin_amdgcn_fdot2(uph(w), uph(a), acc, false);
}
#else
__device__ inline float dot2(unsigned int w, unsigned int a, float acc) {
  half2v wv = uph(w), av = uph(a);
  return acc + (float)wv[0] * (float)av[0] + (float)wv[1] * (float)av[1];
}
#endif

// ---- Head setup: 4 blocks, one per head. q0/kc rows recomputed in-block. ----
__global__ __launch_bounds__(256) void k_heads(const float* __restrict__ cls,
                                               const float* __restrict__ w_qkv,
                                               const float* __restrict__ b_qkv) {
  const int t = threadIdx.x, wvi = t >> 6, l = t & 63;
  const int h = blockIdx.x;
  __shared__ float q0h[64];
  __shared__ float kch[64];
  {
    const int r = t >> 1, half = t & 1;
    const int row = (r < 64) ? (h * 64 + r) : (256 + h * 64 + (r - 64));
    const float4* wp = (const float4*)(w_qkv + (size_t)row * 256 + half * 128);
    const float4* cp = (const float4*)cls + half * 32;
    float a = 0.f;
#pragma unroll 8
    for (int j = 0; j < 32; ++j) {
      float4 w4 = wp[j];
      float4 cv = cp[j];
      a += w4.x * cv.x + w4.y * cv.y + w4.z * cv.z + w4.w * cv.w;
    }
    a += __shfl_xor(a, 1);
    if (half == 0) {
      const float val = a + b_qkv[row];
      if (r < 64) q0h[r] = val; else kch[r - 64] = val;
    }
  }
  __syncthreads();

  float acc = 0.f;
#pragma unroll 8
  for (int j = 0; j < 64; ++j)
    acc += q0h[j] * w_qkv[(size_t)(256 + h * 64 + j) * 256 + t];
  g_qw[h * 256 + t] = acc * 0.125f;
  if (wvi == 0) {
    const float q = q0h[l];
    float pk = q * kch[l];                    // kc includes b_k
    float pb = q * b_qkv[256 + h * 64 + l];
#pragma unroll
    for (int m = 1; m < 64; m <<= 1) {
      pk += __shfl_xor(pk, m);
      pb += __shfl_xor(pb, m);
    }
    if (l == 0) {
      g_s0[h] = pk * 0.125f;
      g_qb[h] = pb * 0.125f;
    }
  }
}

// ---- Attention chunks + rider blocks (proven config: 64-row chunks).
//   blocks 0..1023    : scores + chunk softmax + partial weighted sums
//   blocks 1024..1063 : LDS-tiled transposing f16 casts (feed k_token only)
//   blocks 1064..1127 : v rows of W_qkv·cls + b (wave-per-row 1KB dot) ----
__global__ __launch_bounds__(256) void k_attn(const float* __restrict__ x,
                                              const int* __restrict__ real_cols,
                                              const int* __restrict__ real_rows,
                                              const float* __restrict__ cls,
                                              const float* __restrict__ w_qkv,
                                              const float* __restrict__ b_qkv,
                                              const float* __restrict__ w_out,
                                              const float* __restrict__ w1,
                                              const float* __restrict__ w2) {
  const int t = threadIdx.x, wv = t >> 6, l = t & 63;
  const int bid = blockIdx.x;
  __shared__ __align__(16) char smem[71680];

  if (bid >= 1064) {  // ---- v rows 512..767: wave-per-row dot ----
    const int row = 512 + (bid - 1064) * 4 + wv;
    float4 w4 = *((const float4*)(w_qkv + (size_t)row * 256) + l);
    float4 c4 = *((const float4*)cls + l);
    float a = w4.x * c4.x + w4.y * c4.y + w4.z * c4.z + w4.w * c4.w;
#pragma unroll
    for (int m = 1; m < 64; m <<= 1) a += __shfl_xor(a, m);
    if (l == 0) g_q0kv[row] = a + b_qkv[row];
    return;
  }

  if (bid >= 1024) {  // ---- cast tiles: 64 out-rows x 256 in-cols ----
    const int u = bid - 1024;  // 0..39
    const float* src;
    unsigned short* dst;
    int R, C, o0, e0;
    if (u < 4) { src = w_qkv + 512 * 256; dst = g_wv_hf; R = 256; C = 256; o0 = u * 64; e0 = 0; }
    else if (u < 8) { src = w_out; dst = g_wout_hf; R = 256; C = 256; o0 = (u - 4) * 64; e0 = 0; }
    else if (u < 24) { src = w1; dst = g_w1_hf; R = 1024; C = 256; o0 = (u - 8) * 64; e0 = 0; }
    else { const int v = u - 24; src = w2; dst = g_w2_hf; R = 256; C = 1024; o0 = (v >> 2) * 64; e0 = (v & 3) * 256; }

    unsigned short* tile = (unsigned short*)smem;  // 64*260 ushort = 33280 B
    for (int r = wv; r < 64; r += 4) {
      float4 v = *((const float4*)(src + (size_t)(o0 + r) * C + e0) + l);
      ushort4 ov;
      ov.x = f2h(v.x); ov.y = f2h(v.y); ov.z = f2h(v.z); ov.w = f2h(v.w);
      *(ushort4*)&tile[r * 260 + 4 * l] = ov;
    }
    __syncthreads();
    const int e80 = e0 >> 3;
    for (int e8l = wv; e8l < 32; e8l += 4) {
      const unsigned int* tp = (const unsigned int*)&tile[l * 260 + e8l * 8];
      uint4 o;
      o.x = tp[0]; o.y = tp[1]; o.z = tp[2]; o.w = tp[3];
      *(uint4*)(dst + ((size_t)(e80 + e8l) * R + o0 + l) * 8) = o;
    }
    return;
  }

  // ---- attention chunk blocks (proven 64-row version) ----
  const int bc = bid >> 2, chunk = bid & 3;
  const int b = bc >> 5, c = bc & 31;
  if (c >= real_cols[b]) return;
  const int rr = real_rows[b];
  const int r0 = chunk * 64;
  const int nr = min(64, rr - r0);
  if (nr <= 0) return;

  float (*xs)[260] = (float(*)[260])smem;                    // 66560 B
  float (*qws)[256] = (float(*)[256])(smem + 66560);         //  4096 B
  float (*ps)[64] = (float(*)[64])(smem + 70656);            //  1024 B

#pragma unroll
  for (int i = 0; i < 4; ++i) qws[i][t] = g_qw[i * 256 + t];

  const float* xb = x + ((size_t)bc * kR + r0) * kE;
  for (int r = wv; r < nr; r += 4)
    *(float4*)&xs[r][4 * l] = *(const float4*)(xb + (size_t)r * kE + 4 * l);
  __syncthreads();

  const int h = wv, row = l;
  float acc = 0.f;
  const float4* qrow = (const float4*)&qws[h][0];
  const float4* xrow = (const float4*)&xs[row][0];
#pragma unroll 8
  for (int e4 = 0; e4 < 64; ++e4) {
    float4 q4 = qrow[e4];
    float4 x4 = xrow[e4];
    acc += q4.x * x4.x + q4.y * x4.y + q4.z * x4.z + q4.w * x4.w;
  }
  float s = (row < nr) ? acc + g_qb[h] : -1e30f;
  float mx = s;
#pragma unroll
  for (int m = 1; m < 64; m <<= 1) mx = fmaxf(mx, __shfl_xor(mx, m));
  float p = (row < nr) ? __expf(s - mx) : 0.f;
  float lsum = p;
#pragma unroll
  for (int m = 1; m < 64; m <<= 1) lsum += __shfl_xor(lsum, m);
  ps[h][row] = p;
  if (l == 0) {
    g_m[(bc * 4 + chunk) * 4 + h] = mx;
    g_l[(bc * 4 + chunk) * 4 + h] = lsum;
  }
  __syncthreads();

  float a0 = 0.f, a1 = 0.f, a2 = 0.f, a3 = 0.f;
  for (int r2 = 0; r2 < nr; ++r2) {
    float xv = xs[r2][t];
    a0 += ps[0][r2] * xv;
    a1 += ps[1][r2] * xv;
    a2 += ps[2][r2] * xv;
    a3 += ps[3][r2] * xv;
  }
  float* pp = g_part + (size_t)(bc * 4 + chunk) * 4 * 256;
  pp[0 * 256 + t] = a0;
  pp[1 * 256 + t] = a1;
  pp[2 * 256 + t] = a2;
  pp[3 * 256 + t] = a3;
}

// ---- Fused per-token tail, WIDE. Round-9 change: __launch_bounds__(1024,4)
//      lifts the VGPR cap 64->128 (round-8 lesson: VGPR_Count=56 forced
//      serial load groups -> 85% stall), plus explicit 2-deep software
//      pipelining of the FFN weight-load groups and hoisted ctx/mha loads. ----
__global__ __launch_bounds__(1024, 4) void k_token(const int* __restrict__ real_cols,
                                                   const int* __restrict__ real_rows,
                                                   const float* __restrict__ b_qkv,
                                                   const float* __restrict__ b_out,
                                                   const float* __restrict__ ln_g,
                                                   const float* __restrict__ ln_b,
                                                   const float* __restrict__ b1,
                                                   const float* __restrict__ b2,
                                                   float* __restrict__ out) {
  const int bc = blockIdx.x, b = bc >> 5, c = bc & 31;
  const int t = threadIdx.x, wv = t >> 6, l = t & 63;
  if (c >= real_cols[b]) {  // masked column: write the zero mask and leave
    if (t < 256) out[(size_t)bc * 256 + t] = 0.f;
    return;
  }
  const int rr = real_rows[b];
  const int nch = (rr + 63) >> 6;

  __shared__ float part[4][256];            // split-K partials (reused per phase)
  __shared__ unsigned short xh[4 * 256];    // xbar, f16
  __shared__ unsigned short ctxh[256];      // ctx, f16
  __shared__ float lnsf[256];               // LN output fp32 (exact residual)
  __shared__ unsigned short lnsh[256];      // LN output f16 (dot operand)
  __shared__ unsigned short hsh[1024];      // FFN hidden, f16
  __shared__ float al[4][4];
  __shared__ float p0s[4];
  __shared__ float rb[2][4];

  if (t < 4) {  // flash-merge chunk stats, head h = t
    const int h = t;
    const float s0 = g_s0[h];
    float M = s0;
    for (int ch = 0; ch < nch; ++ch) M = fmaxf(M, g_m[(bc * 4 + ch) * 4 + h]);
    float lt = __expf(s0 - M);
    const float w0 = lt;
    float av[4] = {0.f, 0.f, 0.f, 0.f};
    for (int ch = 0; ch < nch; ++ch) {
      float e = __expf(g_m[(bc * 4 + ch) * 4 + h] - M);
      av[ch] = e;
      lt += g_l[(bc * 4 + ch) * 4 + h] * e;
    }
    const float inv = 1.f / lt;
#pragma unroll
    for (int ch = 0; ch < 4; ++ch) al[h][ch] = av[ch] * inv;
    p0s[h] = w0 * inv;
  }
  __syncthreads();

  {  // xbar merge: thread t -> (h = t>>8, e = t&255); f16 mirror only
    const int h = t >> 8, e = t & 255;
    float a = 0.f;
    for (int ch = 0; ch < nch; ++ch)
      a += al[h][ch] * g_part[(size_t)(bc * 4 + ch) * 1024 + h * 256 + e];
    xh[h * 256 + e] = f2h(a);
  }
  __syncthreads();

  {  // ctx: f = t&255, split-K group q = t>>8; 8 weight loads hoisted
    const int f = t & 255, q = t >> 8, h = f >> 6;
    const uint4* wr = (const uint4*)g_wv_hf;
    const uint4* ap = (const uint4*)&xh[h * 256];
    uint4 wb[8];
#pragma unroll
    for (int i = 0; i < 8; ++i) wb[i] = wr[(q * 8 + i) * 256 + f];
    float acc = 0.f;
#pragma unroll
    for (int i = 0; i < 8; ++i) {
      uint4 a = ap[q * 8 + i];
      acc = dot2(wb[i].x, a.x, acc);
      acc = dot2(wb[i].y, a.y, acc);
      acc = dot2(wb[i].z, a.z, acc);
      acc = dot2(wb[i].w, a.w, acc);
    }
    part[q][f] = acc;
  }
  __syncthreads();
  if (t < 256) {
    const int h = t >> 6;
    const float p0 = p0s[h];
    ctxh[t] = f2h(part[0][t] + part[1][t] + part[2][t] + part[3][t] +
                  p0 * g_q0kv[512 + t] + (1.f - p0) * b_qkv[512 + t]);
  }
  __syncthreads();

  {  // mha: g = t&255, split-K-4 over e8; 8 weight loads hoisted
    const int g = t & 255, q = t >> 8;
    const uint4* wr = (const uint4*)g_wout_hf;
    const uint4* cp = (const uint4*)&ctxh[0];
    uint4 wb[8];
#pragma unroll
    for (int i = 0; i < 8; ++i) wb[i] = wr[(q * 8 + i) * 256 + g];
    float acc = 0.f;
#pragma unroll
    for (int i = 0; i < 8; ++i) {
      uint4 a = cp[q * 8 + i];
      acc = dot2(wb[i].x, a.x, acc);
      acc = dot2(wb[i].y, a.y, acc);
      acc = dot2(wb[i].z, a.z, acc);
      acc = dot2(wb[i].w, a.w, acc);
    }
    part[q][g] = acc;
  }
  __syncthreads();
  if (t < 256) {
    const float mh = part[0][t] + part[1][t] + part[2][t] + part[3][t] + b_out[t];
    float s1 = mh, s2 = mh * mh;
#pragma unroll
    for (int m = 1; m < 64; m <<= 1) {
      s1 += __shfl_xor(s1, m);
      s2 += __shfl_xor(s2, m);
    }
    if (l == 0) {
      rb[0][wv] = s1;
      rb[1][wv] = s2;
    }
    __syncthreads();
    const float mu = (rb[0][0] + rb[0][1] + rb[0][2] + rb[0][3]) * (1.f / 256.f);
    const float msq = (rb[1][0] + rb[1][1] + rb[1][2] + rb[1][3]) * (1.f / 256.f);
    const float var = msq - mu * mu;
    const float lnv = (mh - mu) * rsqrtf(var + 1e-5f) * ln_g[t] + ln_b[t];
    lnsf[t] = lnv;
    lnsh[t] = f2h(lnv);
  } else {
    __syncthreads();
  }
  __syncthreads();

  {  // FFN1: thread t computes f = t; 2-deep pipelined groups of 8 loads
    const uint4* wr = (const uint4*)g_w1_hf;
    const uint4* lp = (const uint4*)&lnsh[0];
    float acc0 = b1[t], acc1 = 0.f;
    uint4 wcur[8], wnxt[8];
#pragma unroll
    for (int i = 0; i < 8; ++i) wcur[i] = wr[i * 1024 + t];
#pragma unroll
    for (int g = 0; g < 4; ++g) {
      if (g < 3) {
#pragma unroll
        for (int i = 0; i < 8; ++i) wnxt[i] = wr[((g + 1) * 8 + i) * 1024 + t];
      }
#pragma unroll
      for (int i = 0; i < 8; ++i) {
        uint4 w = wcur[i];
        uint4 a = lp[g * 8 + i];
        acc0 = dot2(w.x, a.x, acc0);
        acc1 = dot2(w.y, a.y, acc1);
        acc0 = dot2(w.z, a.z, acc0);
        acc1 = dot2(w.w, a.w, acc1);
      }
#pragma unroll
      for (int i = 0; i < 8; ++i) wcur[i] = wnxt[i];
    }
    hsh[t] = f2h(fmaxf(acc0 + acc1, 0.f));
  }
  __syncthreads();

  {  // FFN2: e = t&255, split-K group q = t>>8; 2-deep pipelined groups
    const int e = t & 255, q = t >> 8;
    const uint4* wr = (const uint4*)g_w2_hf;
    const uint4* hp = (const uint4*)&hsh[0];
    float acc0 = 0.f, acc1 = 0.f;
    uint4 wcur[8], wnxt[8];
#pragma unroll
    for (int i = 0; i < 8; ++i) wcur[i] = wr[(q * 32 + i) * 256 + e];
#pragma unroll
    for (int g = 0; g < 4; ++g) {
      if (g < 3) {
#pragma unroll
        for (int i = 0; i < 8; ++i) wnxt[i] = wr[(q * 32 + (g + 1) * 8 + i) * 256 + e];
      }
#pragma unroll
      for (int i = 0; i < 8; ++i) {
        uint4 w = wcur[i];
        uint4 a = hp[q * 32 + g * 8 + i];
        acc0 = dot2(w.x, a.x, acc0);
        acc1 = dot2(w.y, a.y, acc1);
        acc0 = dot2(w.z, a.z, acc0);
        acc1 = dot2(w.w, a.w, acc1);
      }
#pragma unroll
      for (int i = 0; i < 8; ++i) wcur[i] = wnxt[i];
    }
    part[q][e] = acc0 + acc1;
  }
  __syncthreads();
  if (t < 256)
    out[(size_t)bc * 256 + t] =
        lnsf[t] + part[0][t] + part[1][t] + part[2][t] + part[3][t] + b2[t];
}

extern "C" void kernel_launch(void* const* d_in, const int* in_sizes, int n_in,
                              void* d_out, int out_size, void* d_ws, size_t ws_size,
                              hipStream_t stream) {
  const float* x = (const float*)d_in[0];
  const int* real_cols = (const int*)d_in[1];
  const int* real_rows = (const int*)d_in[2];
  const float* cls = (const float*)d_in[3];
  const float* w_qkv = (const float*)d_in[4];
  const float* b_qkv = (const float*)d_in[5];
  const float* w_out = (const float*)d_in[6];
  const float* b_out = (const float*)d_in[7];
  const float* ln_g = (const float*)d_in[8];
  const float* ln_b = (const float*)d_in[9];
  const float* w1 = (const float*)d_in[10];
  const float* b1 = (const float*)d_in[11];
  const float* w2 = (const float*)d_in[12];
  const float* b2 = (const float*)d_in[13];
  float* out = (float*)d_out;
  (void)in_sizes; (void)n_in; (void)out_size; (void)d_ws; (void)ws_size;

  k_heads<<<4, 256, 0, stream>>>(cls, w_qkv, b_qkv);
  k_attn<<<1128, 256, 0, stream>>>(x, real_cols, real_rows, cls, w_qkv, b_qkv, w_out, w1, w2);
  k_token<<<256, 1024, 0, stream>>>(real_cols, real_rows, b_qkv, b_out, ln_g, ln_b, b1, b2, out);
}